// Round 6
// baseline (265.398 us; speedup 1.0000x reference)
//
#include <hip/hip_runtime.h>
#include <hip/hip_bf16.h>

#define BATCH 4
#define SEQ 2048
#define EMBED 512
#define NHEAD 8
#define HDIM 64
#define MTOT (BATCH*SEQ)   // 8192

typedef __attribute__((ext_vector_type(8))) short short8;
typedef __attribute__((ext_vector_type(4))) short short4v;
typedef __attribute__((ext_vector_type(4))) float f32x4;
typedef __attribute__((ext_vector_type(16))) float f32x16;
typedef __attribute__((ext_vector_type(4))) unsigned int uint4v;

#define GLOBAL_AS __attribute__((address_space(1)))
#define LDS_AS __attribute__((address_space(3)))

__device__ __forceinline__ void gload_lds16(const void* g, void* l) {
  __builtin_amdgcn_global_load_lds((const GLOBAL_AS void*)g, (LDS_AS void*)l, 16, 0, 0);
}

__device__ __forceinline__ unsigned short f2bf(float x) {
  unsigned u = __builtin_bit_cast(unsigned, x);
  unsigned r = (u + 0x7FFFu + ((u >> 16) & 1u)) >> 16;
  return (unsigned short)r;
}

// pack two floats to bf16x2 word via compiler cvt (emits v_cvt_pk_bf16_f32)
__device__ __forceinline__ unsigned pk32(float a, float b) {
  unsigned short ua = __builtin_bit_cast(unsigned short, __float2bfloat16(a));
  unsigned short ub = __builtin_bit_cast(unsigned short, __float2bfloat16(b));
  return (unsigned)ua | ((unsigned)ub << 16);
}

__device__ __forceinline__ short8 pack8(f32x4 a, f32x4 b) {
  uint4v u = {pk32(a[0], a[1]), pk32(a[2], a[3]), pk32(b[0], b[1]), pk32(b[2], b[3])};
  return __builtin_bit_cast(short8, u);
}

// ---------------- fp32 -> bf16 convert (weights) ----------------
__global__ __launch_bounds__(256) void k_cvt(const float* __restrict__ src,
                                             unsigned short* __restrict__ dst, int n4) {
  int i = blockIdx.x * 256 + threadIdx.x;
  if (i < n4) {
    f32x4 f = ((const f32x4*)src)[i];
    short4v s;
    s[0]=(short)f2bf(f[0]); s[1]=(short)f2bf(f[1]); s[2]=(short)f2bf(f[2]); s[3]=(short)f2bf(f[3]);
    ((short4v*)dst)[i] = s;
  }
}

// ---------------- fused input projection GEMM (fused fp32->bf16 A) ---------
// z=0: Q*(log2e/8) -> Qg [b,h,s,d]; z=1: K -> Kg [b,h,s,d]; z=2: V -> VTg [b,h,d,s]
__global__ __launch_bounds__(256) void k_proj(
    const float* __restrict__ query, const float* __restrict__ key,
    const float* __restrict__ value, const unsigned short* __restrict__ Wbf,
    const float* __restrict__ bias,
    unsigned short* __restrict__ Qg, unsigned short* __restrict__ Kg,
    unsigned short* __restrict__ VTg) {
  __shared__ __align__(16) unsigned short As[128 * 64];
  __shared__ __align__(16) unsigned short Bs[128 * 64];
  const int tid = threadIdx.x;
  const int lane = tid & 63, w = tid >> 6;
  const int wr = w >> 1, wc = w & 1;
  const int m0 = blockIdx.x * 128, n0 = blockIdx.y * 128, z = blockIdx.z;
  const float* X = (z == 0) ? query : (z == 1) ? key : value;

  f32x4 acc[4][4];
#pragma unroll
  for (int a = 0; a < 4; ++a)
#pragma unroll
    for (int b = 0; b < 4; ++b) acc[a][b] = (f32x4){0.f, 0.f, 0.f, 0.f};

  for (int kt = 0; kt < 8; ++kt) {
#pragma unroll
    for (int i = 0; i < 4; ++i) {
      int cid = i * 256 + tid;
      int row = cid >> 3, c = cid & 7;
      const float* ap = X + (size_t)(m0 + row) * EMBED + kt * 64 + c * 8;
      f32x4 f0 = *(const f32x4*)ap;
      f32x4 f1 = *(const f32x4*)(ap + 4);
      *(short8*)((char*)As + row * 128 + ((c ^ (row & 7)) << 4)) = pack8(f0, f1);
    }
#pragma unroll
    for (int i = 0; i < 4; ++i) {
      int cb = w * 256 + i * 64;
      int chunk = cb + lane;
      int row = chunk >> 3, cs = chunk & 7;
      gload_lds16(Wbf + (size_t)(z * EMBED + n0 + row) * EMBED + kt * 64 + ((cs ^ (row & 7)) << 3),
                  (char*)Bs + cb * 16);
    }
    __syncthreads();
#pragma unroll
    for (int kk = 0; kk < 2; ++kk) {
      short8 af[4], bfr[4];
      int dc = kk * 4 + (lane >> 4);
#pragma unroll
      for (int mf = 0; mf < 4; ++mf) {
        int row = wr * 64 + mf * 16 + (lane & 15);
        af[mf] = *(const short8*)((const char*)As + row * 128 + ((dc ^ (row & 7)) << 4));
      }
#pragma unroll
      for (int nf = 0; nf < 4; ++nf) {
        int row = wc * 64 + nf * 16 + (lane & 15);
        bfr[nf] = *(const short8*)((const char*)Bs + row * 128 + ((dc ^ (row & 7)) << 4));
      }
#pragma unroll
      for (int mf = 0; mf < 4; ++mf)
#pragma unroll
        for (int nf = 0; nf < 4; ++nf)
          acc[mf][nf] = __builtin_amdgcn_mfma_f32_16x16x32_bf16(af[mf], bfr[nf], acc[mf][nf], 0, 0, 0);
    }
    __syncthreads();
  }

  const float SCALE = 0.18033688011112042f;  // log2(e)/8
#pragma unroll
  for (int mf = 0; mf < 4; ++mf) {
#pragma unroll
    for (int nf = 0; nf < 4; ++nf) {
      int ncol = n0 + wc * 64 + nf * 16 + (lane & 15);
      float bv = bias[z * EMBED + ncol];
      int h = ncol >> 6, dd = ncol & 63;
      if (z == 2) {
        int mrow0 = m0 + wr * 64 + mf * 16 + (lane >> 4) * 4;
        int b = mrow0 >> 11, s0 = mrow0 & 2047;
        short4v pv;
#pragma unroll
        for (int r = 0; r < 4; ++r) pv[r] = (short)f2bf(acc[mf][nf][r] + bv);
        *(short4v*)(VTg + ((size_t)(b * NHEAD + h) * HDIM + dd) * SEQ + s0) = pv;
      } else {
        unsigned short* dst = (z == 0) ? Qg : Kg;
        float sc = (z == 0) ? SCALE : 1.0f;
#pragma unroll
        for (int r = 0; r < 4; ++r) {
          int mrow = m0 + wr * 64 + mf * 16 + (lane >> 4) * 4 + r;
          int b = mrow >> 11, s = mrow & 2047;
          dst[((size_t)(b * NHEAD + h) * SEQ + s) * HDIM + dd] = f2bf((acc[mf][nf][r] + bv) * sc);
        }
      }
    }
  }
}

// ---------------- flash attention: swapped-QK^T 32x32, KV-split-4, no staging
// grid: (B*H, SEQ/32). Block = 4 waves, wave wk handles keys 32*wk of each
// 128-key tile. K/V read directly from global (L2-resident per XCD affinity).
// Exact tree-merge of the 4 (m,l,o) partitions via LDS at the end.
__global__ __launch_bounds__(256, 4) void k_attn(
    const unsigned short* __restrict__ Qg, const unsigned short* __restrict__ Kg,
    const unsigned short* __restrict__ VTg, unsigned short* __restrict__ AO) {
  __shared__ float Ms[2][64], Ls[2][64];
  __shared__ __align__(16) float Os[2][32][64];
  const int tid = threadIdx.x, lane = tid & 63, wk = tid >> 6;
  const int hi = lane >> 5, lq = lane & 31;
  const int bh = blockIdx.x;                 // bh -> XCD affinity (bh%8)
  const int q0 = blockIdx.y * 32;

  // Q fragments (B-operand of swapped QK^T): qf[ks] = Q[q0+lq][16*ks + 8*hi + e]
  short8 qf[4];
  {
    const unsigned short* qp = Qg + ((size_t)bh * SEQ + q0 + lq) * HDIM + 8 * hi;
#pragma unroll
    for (int ks = 0; ks < 4; ++ks) qf[ks] = *(const short8*)(qp + 16 * ks);
  }

  // per-tile base pointers for this wave's 32-key slice
  const unsigned short* Kb0 = Kg + ((size_t)bh * SEQ + 32 * wk + lq) * HDIM + 8 * hi;
  const unsigned short* Vb0 = VTg + (size_t)bh * (HDIM * SEQ) + (size_t)lq * SEQ + 32 * wk + 8 * hi;

  f32x16 o0, o1;
#pragma unroll
  for (int r = 0; r < 16; ++r) { o0[r] = 0.f; o1[r] = 0.f; }
  float m_run = -__builtin_inff(), l_run = 0.f;

  for (int t = 0; t < 16; ++t) {
    const unsigned short* Kt = Kb0 + (size_t)t * 128 * HDIM;
    const unsigned short* Vt = Vb0 + t * 128;

    // K fragments: A[m=key(32wk+lq)][k=16ks+8hi+e]
    short8 kf0 = *(const short8*)(Kt);
    short8 kf1 = *(const short8*)(Kt + 16);
    short8 kf2 = *(const short8*)(Kt + 32);
    short8 kf3 = *(const short8*)(Kt + 48);

    f32x16 sS;
#pragma unroll
    for (int r = 0; r < 16; ++r) sS[r] = 0.f;
    __builtin_amdgcn_s_setprio(1);
    sS = __builtin_amdgcn_mfma_f32_32x32x16_bf16(kf0, qf[0], sS, 0, 0, 0);
    sS = __builtin_amdgcn_mfma_f32_32x32x16_bf16(kf1, qf[1], sS, 0, 0, 0);
    sS = __builtin_amdgcn_mfma_f32_32x32x16_bf16(kf2, qf[2], sS, 0, 0, 0);
    sS = __builtin_amdgcn_mfma_f32_32x32x16_bf16(kf3, qf[3], sS, 0, 0, 0);
    __builtin_amdgcn_s_setprio(0);

    // V fragments issued now: their ~L2 latency hides under softmax VALU.
    // B[k=keyslot 16c+8hi+e][n=d]; d = lq (v0*) and 32+lq (v1*)
    short8 v00 = *(const short8*)(Vt);
    short8 v01 = *(const short8*)(Vt + 16);
    short8 v10 = *(const short8*)(Vt + 32 * SEQ);
    short8 v11 = *(const short8*)(Vt + 32 * SEQ + 16);

    // ---- online softmax (tree reduce; partner via shfl_xor 32) ----
    float mx[8];
#pragma unroll
    for (int r = 0; r < 8; ++r) mx[r] = fmaxf(sS[r], sS[r + 8]);
#pragma unroll
    for (int r = 0; r < 4; ++r) mx[r] = fmaxf(mx[r], mx[r + 4]);
    float pm = fmaxf(fmaxf(mx[0], mx[1]), fmaxf(mx[2], mx[3]));
    float pmf = fmaxf(pm, __shfl_xor(pm, 32));

    if (__any(pmf > m_run + 8.0f)) {  // defer-max
      float mnew = fmaxf(m_run, pmf);
      float alpha = exp2f(m_run - mnew);
      m_run = mnew;
      l_run *= alpha;
#pragma unroll
      for (int r = 0; r < 16; ++r) {
        int qi = (r & 3) + 8 * (r >> 2) + 4 * hi;
        float ar = __shfl(alpha, qi);
        o0[r] *= ar;
        o1[r] *= ar;
      }
    }

#pragma unroll
    for (int r = 0; r < 16; ++r) sS[r] = exp2f(sS[r] - m_run);
    float sm[8];
#pragma unroll
    for (int r = 0; r < 8; ++r) sm[r] = sS[r] + sS[r + 8];
#pragma unroll
    for (int r = 0; r < 4; ++r) sm[r] += sm[r + 4];
    float rs = (sm[0] + sm[1]) + (sm[2] + sm[3]);
    l_run += rs + __shfl_xor(rs, 32);

    // ---- P -> bf16 PV A-fragments via pack + shfl_xor(32) + select ----
    unsigned W0[4], W1[4];
#pragma unroll
    for (int g = 0; g < 4; ++g) {
      W0[g] = pk32(sS[4 * g + 0], sS[4 * g + 1]);
      W1[g] = pk32(sS[4 * g + 2], sS[4 * g + 3]);
    }
    short8 pa[2];
#pragma unroll
    for (int c = 0; c < 2; ++c) {
      unsigned a0 = W0[2 * c], a1 = W0[2 * c + 1];
      unsigned b0 = W1[2 * c], b1 = W1[2 * c + 1];
      unsigned sa0 = (unsigned)__shfl_xor((int)a0, 32);
      unsigned sa1 = (unsigned)__shfl_xor((int)a1, 32);
      unsigned sb0 = (unsigned)__shfl_xor((int)b0, 32);
      unsigned sb1 = (unsigned)__shfl_xor((int)b1, 32);
      unsigned w0 = hi ? sa1 : a0;   // keyslot 16c+8hi+{0,1}
      unsigned w1 = hi ? sb1 : b0;   // +{2,3}
      unsigned w2 = hi ? a1 : sa0;   // +{4,5}
      unsigned w3 = hi ? b1 : sb0;   // +{6,7}
      pa[c] = __builtin_bit_cast(short8, (uint4v){w0, w1, w2, w3});
    }

    // ---- O += P V ----
    __builtin_amdgcn_s_setprio(1);
    o0 = __builtin_amdgcn_mfma_f32_32x32x16_bf16(pa[0], v00, o0, 0, 0, 0);
    o0 = __builtin_amdgcn_mfma_f32_32x32x16_bf16(pa[1], v01, o0, 0, 0, 0);
    o1 = __builtin_amdgcn_mfma_f32_32x32x16_bf16(pa[0], v10, o1, 0, 0, 0);
    o1 = __builtin_amdgcn_mfma_f32_32x32x16_bf16(pa[1], v11, o1, 0, 0, 0);
    __builtin_amdgcn_s_setprio(0);
  }

  // ---- exact tree-merge of 4 partitions: (0,1),(2,3) then (0,2) ----
  if (wk & 1) {
    int s = wk >> 1;
    Ms[s][lane] = m_run;
    Ls[s][lane] = l_run;
#pragma unroll
    for (int r = 0; r < 16; ++r) {
      Os[s][r][lane] = o0[r];
      Os[s][16 + r][lane] = o1[r];
    }
  }
  __syncthreads();
  if (!(wk & 1)) {
    int s = wk >> 1;
    float m2 = Ms[s][lane], l2 = Ls[s][lane];
    float mm = fmaxf(m_run, m2);
    float a1 = exp2f(m_run - mm), a2 = exp2f(m2 - mm);
    m_run = mm;
    l_run = l_run * a1 + l2 * a2;
#pragma unroll
    for (int r = 0; r < 16; ++r) {
      int qi = (r & 3) + 8 * (r >> 2) + 4 * hi;
      float A1 = __shfl(a1, qi), A2 = __shfl(a2, qi);
      o0[r] = o0[r] * A1 + Os[s][r][lane] * A2;
      o1[r] = o1[r] * A1 + Os[s][16 + r][lane] * A2;
    }
  }
  __syncthreads();
  if (wk == 2) {
    Ms[0][lane] = m_run;
    Ls[0][lane] = l_run;
#pragma unroll
    for (int r = 0; r < 16; ++r) {
      Os[0][r][lane] = o0[r];
      Os[0][16 + r][lane] = o1[r];
    }
  }
  __syncthreads();
  if (wk == 0) {
    const int bb = bh >> 3, h = bh & 7;
    float m2 = Ms[0][lane], l2 = Ls[0][lane];
    float mm = fmaxf(m_run, m2);
    float a1 = exp2f(m_run - mm), a2 = exp2f(m2 - mm);
    float linv = 1.0f / (l_run * a1 + l2 * a2);
#pragma unroll
    for (int r = 0; r < 16; ++r) {
      int qi = (r & 3) + 8 * (r >> 2) + 4 * hi;
      float A1 = __shfl(a1, qi), A2 = __shfl(a2, qi), LI = __shfl(linv, qi);
      float e0 = (o0[r] * A1 + Os[0][r][lane] * A2) * LI;
      float e1 = (o1[r] * A1 + Os[0][16 + r][lane] * A2) * LI;
      size_t base = ((size_t)bb * SEQ + q0 + qi) * EMBED + h * 64;
      AO[base + lq] = f2bf(e0);
      AO[base + 32 + lq] = f2bf(e1);
    }
  }
}

// ---------------- output projection GEMM ----------------
__global__ __launch_bounds__(256) void k_outproj(
    const unsigned short* __restrict__ AO, const unsigned short* __restrict__ Wo,
    const float* __restrict__ bias, float* __restrict__ out) {
  __shared__ __align__(16) unsigned short As[128 * 64];
  __shared__ __align__(16) unsigned short Bs[128 * 64];
  const int tid = threadIdx.x;
  const int lane = tid & 63, w = tid >> 6;
  const int wr = w >> 1, wc = w & 1;
  const int m0 = blockIdx.x * 128, n0 = blockIdx.y * 128;

  f32x4 acc[4][4];
#pragma unroll
  for (int a = 0; a < 4; ++a)
#pragma unroll
    for (int b = 0; b < 4; ++b) acc[a][b] = (f32x4){0.f, 0.f, 0.f, 0.f};

  for (int kt = 0; kt < 8; ++kt) {
#pragma unroll
    for (int i = 0; i < 4; ++i) {
      int cb = w * 256 + i * 64;
      int chunk = cb + lane;
      int row = chunk >> 3, cs = chunk & 7;
      gload_lds16(AO + (size_t)(m0 + row) * EMBED + kt * 64 + ((cs ^ (row & 7)) << 3),
                  (char*)As + cb * 16);
      gload_lds16(Wo + (size_t)(n0 + row) * EMBED + kt * 64 + ((cs ^ (row & 7)) << 3),
                  (char*)Bs + cb * 16);
    }
    __syncthreads();
#pragma unroll
    for (int kk = 0; kk < 2; ++kk) {
      short8 af[4], bfr[4];
      int dc = kk * 4 + (lane >> 4);
#pragma unroll
      for (int mf = 0; mf < 4; ++mf) {
        int row = wr * 64 + mf * 16 + (lane & 15);
        af[mf] = *(const short8*)((const char*)As + row * 128 + ((dc ^ (row & 7)) << 4));
      }
#pragma unroll
      for (int nf = 0; nf < 4; ++nf) {
        int row = wc * 64 + nf * 16 + (lane & 15);
        bfr[nf] = *(const short8*)((const char*)Bs + row * 128 + ((dc ^ (row & 7)) << 4));
      }
#pragma unroll
      for (int mf = 0; mf < 4; ++mf)
#pragma unroll
        for (int nf = 0; nf < 4; ++nf)
          acc[mf][nf] = __builtin_amdgcn_mfma_f32_16x16x32_bf16(af[mf], bfr[nf], acc[mf][nf], 0, 0, 0);
    }
    __syncthreads();
  }

#pragma unroll
  for (int mf = 0; mf < 4; ++mf)
#pragma unroll
    for (int nf = 0; nf < 4; ++nf) {
      int ncol = n0 + wc * 64 + nf * 16 + (lane & 15);
      float bv = bias[ncol];
#pragma unroll
      for (int r = 0; r < 4; ++r) {
        int mrow = m0 + wr * 64 + mf * 16 + (lane >> 4) * 4 + r;
        out[(size_t)mrow * EMBED + ncol] = acc[mf][nf][r] + bv;
      }
    }
}

extern "C" void kernel_launch(void* const* d_in, const int* in_sizes, int n_in,
                              void* d_out, int out_size, void* d_ws, size_t ws_size,
                              hipStream_t stream) {
  const float* query = (const float*)d_in[0];
  const float* key   = (const float*)d_in[1];
  const float* value = (const float*)d_in[2];
  const float* win   = (const float*)d_in[3];
  const float* bin   = (const float*)d_in[4];
  const float* wout  = (const float*)d_in[5];
  const float* bout  = (const float*)d_in[6];
  float* out = (float*)d_out;

  char* ws = (char*)d_ws;
  unsigned short* Wbf  = (unsigned short*)(ws);              // 1.5 MB
  unsigned short* Wobf = (unsigned short*)(ws + 0x180000);   // 0.5 MB
  unsigned short* Qg   = (unsigned short*)(ws + 0x200000);   // 8 MB
  unsigned short* Kg   = (unsigned short*)(ws + 0xA00000);   // 8 MB
  unsigned short* VTg  = (unsigned short*)(ws + 0x1200000);  // 8 MB
  unsigned short* AO   = (unsigned short*)(ws + 0x1A00000);  // 8 MB

  k_cvt<<<768, 256, 0, stream>>>(win, Wbf, 196608);
  k_cvt<<<256, 256, 0, stream>>>(wout, Wobf, 65536);
  k_proj<<<dim3(64, 4, 3), 256, 0, stream>>>(query, key, value, Wbf, bin, Qg, Kg, VTg);
  k_attn<<<dim3(32, 64), 256, 0, stream>>>(Qg, Kg, VTg, AO);
  k_outproj<<<dim3(64, 4), 256, 0, stream>>>(AO, Wobf, bout, out);
}

// Round 8
// 217.957 us; speedup vs baseline: 1.2177x; 1.2177x over previous
//
#include <hip/hip_runtime.h>
#include <hip/hip_bf16.h>

#define BATCH 4
#define SEQ 2048
#define EMBED 512
#define NHEAD 8
#define HDIM 64
#define MTOT (BATCH*SEQ)   // 8192

typedef __attribute__((ext_vector_type(8))) short short8;
typedef __attribute__((ext_vector_type(4))) short short4v;
typedef __attribute__((ext_vector_type(4))) float f32x4;
typedef __attribute__((ext_vector_type(16))) float f32x16;
typedef __attribute__((ext_vector_type(4))) unsigned int uint4v;

#define GLOBAL_AS __attribute__((address_space(1)))
#define LDS_AS __attribute__((address_space(3)))

__device__ __forceinline__ void gload_lds16(const void* g, void* l) {
  __builtin_amdgcn_global_load_lds((const GLOBAL_AS void*)g, (LDS_AS void*)l, 16, 0, 0);
}

__device__ __forceinline__ unsigned short f2bf(float x) {
  unsigned u = __builtin_bit_cast(unsigned, x);
  unsigned r = (u + 0x7FFFu + ((u >> 16) & 1u)) >> 16;
  return (unsigned short)r;
}

// pack two floats to bf16x2 word via compiler cvt (emits v_cvt_pk_bf16_f32)
__device__ __forceinline__ unsigned pk32(float a, float b) {
  unsigned short ua = __builtin_bit_cast(unsigned short, __float2bfloat16(a));
  unsigned short ub = __builtin_bit_cast(unsigned short, __float2bfloat16(b));
  return (unsigned)ua | ((unsigned)ub << 16);
}

__device__ __forceinline__ short8 pack8(f32x4 a, f32x4 b) {
  uint4v u = {pk32(a[0], a[1]), pk32(a[2], a[3]), pk32(b[0], b[1]), pk32(b[2], b[3])};
  return __builtin_bit_cast(short8, u);
}

// ---------------- weights fp32 -> bf16 (both weights, one launch) ----------
__global__ __launch_bounds__(256) void k_cvtw(const float* __restrict__ w1,
                                              unsigned short* __restrict__ d1,
                                              const float* __restrict__ w2,
                                              unsigned short* __restrict__ d2) {
  int i = blockIdx.x * 256 + threadIdx.x;
  const float* src;
  unsigned short* dst;
  int j;
  if (i < 196608) { src = w1; dst = d1; j = i; }
  else            { src = w2; dst = d2; j = i - 196608; }
  f32x4 f = ((const f32x4*)src)[j];
  short4v s;
  s[0]=(short)f2bf(f[0]); s[1]=(short)f2bf(f[1]); s[2]=(short)f2bf(f[2]); s[3]=(short)f2bf(f[3]);
  ((short4v*)dst)[j] = s;
}

// ---------------- fused input projection GEMM -------------------------------
// A staged as RAW fp32 via global_load_lds (no reg round-trip); bf16 convert
// happens in the fragment read (pk32 x4). LDS A chunk c of row holds source
// chunk c^(row&15)  (16B chunks; 16 per 64-f32 row).
// z=0: Q*(log2e/8) -> Qg [b,h,s,d]; z=1: K -> Kg [b,h,s,d]; z=2: V -> VTg [b,h,d,s]
__global__ __launch_bounds__(256) void k_proj(
    const float* __restrict__ query, const float* __restrict__ key,
    const float* __restrict__ value, const unsigned short* __restrict__ Wbf,
    const float* __restrict__ bias,
    unsigned short* __restrict__ Qg, unsigned short* __restrict__ Kg,
    unsigned short* __restrict__ VTg) {
  __shared__ __align__(16) float Asf[128 * 64];           // 32 KB
  __shared__ __align__(16) unsigned short Bs[128 * 64];   // 16 KB
  const int tid = threadIdx.x;
  const int lane = tid & 63, w = tid >> 6;
  const int wr = w >> 1, wc = w & 1;
  const int m0 = blockIdx.x * 128, n0 = blockIdx.y * 128, z = blockIdx.z;
  const float* X = (z == 0) ? query : (z == 1) ? key : value;

  f32x4 acc[4][4];
#pragma unroll
  for (int a = 0; a < 4; ++a)
#pragma unroll
    for (int b = 0; b < 4; ++b) acc[a][b] = (f32x4){0.f, 0.f, 0.f, 0.f};

  for (int kt = 0; kt < 8; ++kt) {
    // stage A: 128 rows x 64 f32 = 2048 x 16B chunks, 8 per thread
#pragma unroll
    for (int i = 0; i < 8; ++i) {
      int cid = i * 256 + tid;
      int row = cid >> 4, c = cid & 15;
      int cp = c ^ (row & 15);  // source chunk (4 f32)
      gload_lds16(X + (size_t)(m0 + row) * EMBED + kt * 64 + cp * 4,
                  (char*)Asf + cid * 16);
    }
    // stage B (bf16 weights), 8-chunk rows, XOR row&7 swizzle
#pragma unroll
    for (int i = 0; i < 4; ++i) {
      int cb = w * 256 + i * 64;
      int chunk = cb + lane;
      int row = chunk >> 3, cs = chunk & 7;
      gload_lds16(Wbf + (size_t)(z * EMBED + n0 + row) * EMBED + kt * 64 + ((cs ^ (row & 7)) << 3),
                  (char*)Bs + cb * 16);
    }
    __syncthreads();
#pragma unroll
    for (int kk = 0; kk < 2; ++kk) {
      short8 af[4], bfr[4];
      int dc = kk * 4 + (lane >> 4);
#pragma unroll
      for (int mf = 0; mf < 4; ++mf) {
        int row = wr * 64 + mf * 16 + (lane & 15);
        const char* Ab = (const char*)Asf + row * 256;
        f32x4 f0 = *(const f32x4*)(Ab + (((2 * dc) ^ (row & 15)) << 4));
        f32x4 f1 = *(const f32x4*)(Ab + (((2 * dc + 1) ^ (row & 15)) << 4));
        af[mf] = pack8(f0, f1);
      }
#pragma unroll
      for (int nf = 0; nf < 4; ++nf) {
        int row = wc * 64 + nf * 16 + (lane & 15);
        bfr[nf] = *(const short8*)((const char*)Bs + row * 128 + ((dc ^ (row & 7)) << 4));
      }
#pragma unroll
      for (int mf = 0; mf < 4; ++mf)
#pragma unroll
        for (int nf = 0; nf < 4; ++nf)
          acc[mf][nf] = __builtin_amdgcn_mfma_f32_16x16x32_bf16(af[mf], bfr[nf], acc[mf][nf], 0, 0, 0);
    }
    __syncthreads();
  }

  const float SCALE = 0.18033688011112042f;  // log2(e)/8
#pragma unroll
  for (int mf = 0; mf < 4; ++mf) {
#pragma unroll
    for (int nf = 0; nf < 4; ++nf) {
      int ncol = n0 + wc * 64 + nf * 16 + (lane & 15);
      float bv = bias[z * EMBED + ncol];
      int h = ncol >> 6, dd = ncol & 63;
      if (z == 2) {
        int mrow0 = m0 + wr * 64 + mf * 16 + (lane >> 4) * 4;
        int b = mrow0 >> 11, s0 = mrow0 & 2047;
        short4v pv;
#pragma unroll
        for (int r = 0; r < 4; ++r) pv[r] = (short)f2bf(acc[mf][nf][r] + bv);
        *(short4v*)(VTg + ((size_t)(b * NHEAD + h) * HDIM + dd) * SEQ + s0) = pv;
      } else {
        unsigned short* dst = (z == 0) ? Qg : Kg;
        float sc = (z == 0) ? SCALE : 1.0f;
#pragma unroll
        for (int r = 0; r < 4; ++r) {
          int mrow = m0 + wr * 64 + mf * 16 + (lane >> 4) * 4 + r;
          int b = mrow >> 11, s = mrow & 2047;
          dst[((size_t)(b * NHEAD + h) * SEQ + s) * HDIM + dd] = f2bf((acc[mf][nf][r] + bv) * sc);
        }
      }
    }
  }
}

// ---------------- flash attention: swapped-QK^T 32x32, KV-split-2 ----------
// (round-5 verified kernel, verbatim: 89.5 us, absmax at bf16 floor)
// grid: (B*H, SEQ/64). Block = 4 waves: wq in {0,1} picks 32 q-rows,
// wk in {0,1} picks half of each 64-key tile. Exact (m,l,o) merge at end.
__global__ __launch_bounds__(256, 4) void k_attn(
    const unsigned short* __restrict__ Qg, const unsigned short* __restrict__ Kg,
    const unsigned short* __restrict__ VTg, unsigned short* __restrict__ AO) {
  __shared__ __align__(16) char smem[32768];  // [K dbuf 16KB][V dbuf 16KB]; reused for merge
  const int tid = threadIdx.x, lane = tid & 63, w = tid >> 6;
  const int wq = w >> 1, wk = w & 1;
  const int hi = lane >> 5, lq = lane & 31;
  const int bh = blockIdx.x;                    // bh -> XCD affinity (bh%8)
  const int q0 = blockIdx.y * 64 + wq * 32;

  short8 qf[4];
  {
    const unsigned short* qp = Qg + ((size_t)bh * SEQ + q0 + lq) * HDIM + 8 * hi;
#pragma unroll
    for (int ks = 0; ks < 4; ++ks) qf[ks] = *(const short8*)(qp + 16 * ks);
  }

  f32x16 o0, o1;
#pragma unroll
  for (int r = 0; r < 16; ++r) { o0[r] = 0.f; o1[r] = 0.f; }
  float m_run = -__builtin_inff(), l_run = 0.f;

#define STAGE(buf, t)                                                                     \
  do {                                                                                    \
    int kv0_ = (t) * 64;                                                                  \
    _Pragma("unroll")                                                                     \
    for (int i_ = 0; i_ < 2; ++i_) {                                                      \
      int cid_ = i_ * 256 + tid;                                                          \
      int row_ = cid_ >> 3, c_ = cid_ & 7;                                                \
      gload_lds16(Kg + ((size_t)bh * SEQ + kv0_ + row_) * HDIM + 8 * (c_ ^ (row_ & 7)),   \
                  smem + (buf) * 8192 + cid_ * 16);                                       \
      gload_lds16(VTg + ((size_t)bh * HDIM + row_) * SEQ + kv0_ + 8 * (c_ ^ (row_ & 7)),  \
                  smem + 16384 + (buf) * 8192 + cid_ * 16);                               \
    }                                                                                     \
  } while (0)

  STAGE(0, 0);

  for (int t = 0; t < 32; ++t) {
    const int buf = t & 1;
    __syncthreads();
    if (t + 1 < 32) STAGE(buf ^ 1, t + 1);

    const char* Kb = smem + buf * 8192;
    const char* Vb = smem + 16384 + buf * 8192;

    f32x16 sS;
#pragma unroll
    for (int r = 0; r < 16; ++r) sS[r] = 0.f;
    __builtin_amdgcn_s_setprio(1);
#pragma unroll
    for (int ks = 0; ks < 4; ++ks) {
      short8 kf = *(const short8*)(Kb + (32 * wk + lq) * 128 + (((2 * ks + hi) ^ (lq & 7)) << 4));
      sS = __builtin_amdgcn_mfma_f32_32x32x16_bf16(kf, qf[ks], sS, 0, 0, 0);
    }
    __builtin_amdgcn_s_setprio(0);

    float mx[8];
#pragma unroll
    for (int r = 0; r < 8; ++r) mx[r] = fmaxf(sS[r], sS[r + 8]);
#pragma unroll
    for (int r = 0; r < 4; ++r) mx[r] = fmaxf(mx[r], mx[r + 4]);
    float pm = fmaxf(fmaxf(mx[0], mx[1]), fmaxf(mx[2], mx[3]));
    float pmf = fmaxf(pm, __shfl_xor(pm, 32));

    if (__any(pmf > m_run + 8.0f)) {  // defer-max
      float mnew = fmaxf(m_run, pmf);
      float alpha = exp2f(m_run - mnew);
      m_run = mnew;
      l_run *= alpha;
#pragma unroll
      for (int r = 0; r < 16; ++r) {
        int qi = (r & 3) + 8 * (r >> 2) + 4 * hi;
        float ar = __shfl(alpha, qi);
        o0[r] *= ar;
        o1[r] *= ar;
      }
    }

#pragma unroll
    for (int r = 0; r < 16; ++r) sS[r] = exp2f(sS[r] - m_run);
    float sm[8];
#pragma unroll
    for (int r = 0; r < 8; ++r) sm[r] = sS[r] + sS[r + 8];
#pragma unroll
    for (int r = 0; r < 4; ++r) sm[r] += sm[r + 4];
    float rs = (sm[0] + sm[1]) + (sm[2] + sm[3]);
    l_run += rs + __shfl_xor(rs, 32);

    unsigned W0[4], W1[4];
#pragma unroll
    for (int g = 0; g < 4; ++g) {
      W0[g] = pk32(sS[4 * g + 0], sS[4 * g + 1]);
      W1[g] = pk32(sS[4 * g + 2], sS[4 * g + 3]);
    }
    short8 pa[2];
#pragma unroll
    for (int c = 0; c < 2; ++c) {
      unsigned a0 = W0[2 * c], a1 = W0[2 * c + 1];
      unsigned b0 = W1[2 * c], b1 = W1[2 * c + 1];
      unsigned sa0 = (unsigned)__shfl_xor((int)a0, 32);
      unsigned sa1 = (unsigned)__shfl_xor((int)a1, 32);
      unsigned sb0 = (unsigned)__shfl_xor((int)b0, 32);
      unsigned sb1 = (unsigned)__shfl_xor((int)b1, 32);
      unsigned w0 = hi ? sa1 : a0;
      unsigned w1 = hi ? sb1 : b0;
      unsigned w2 = hi ? a1 : sa0;
      unsigned w3 = hi ? b1 : sb0;
      pa[c] = __builtin_bit_cast(short8, (uint4v){w0, w1, w2, w3});
    }

    __builtin_amdgcn_s_setprio(1);
#pragma unroll
    for (int c = 0; c < 2; ++c) {
      int sw = ((4 * wk + 2 * c + hi) ^ (lq & 7)) << 4;
      short8 v0 = *(const short8*)(Vb + lq * 128 + sw);
      short8 v1 = *(const short8*)(Vb + (32 + lq) * 128 + sw);
      o0 = __builtin_amdgcn_mfma_f32_32x32x16_bf16(pa[c], v0, o0, 0, 0, 0);
      o1 = __builtin_amdgcn_mfma_f32_32x32x16_bf16(pa[c], v1, o1, 0, 0, 0);
    }
    __builtin_amdgcn_s_setprio(0);
  }
#undef STAGE

  __syncthreads();
  float* Ml = (float*)smem;
  float* Ll = Ml + 128;
  float* Ol = (float*)(smem + 1024);
  if (wk == 1) {
    Ml[wq * 64 + lane] = m_run;
    Ll[wq * 64 + lane] = l_run;
#pragma unroll
    for (int r = 0; r < 16; ++r) {
      Ol[(wq * 32 + r) * 64 + lane] = o0[r];
      Ol[(wq * 32 + 16 + r) * 64 + lane] = o1[r];
    }
  }
  __syncthreads();
  if (wk == 0) {
    const int bb = bh >> 3, h = bh & 7;
    float m2 = Ml[wq * 64 + lane];
    float l2 = Ll[wq * 64 + lane];
    float mm = fmaxf(m_run, m2);
    float a1 = exp2f(m_run - mm), a2 = exp2f(m2 - mm);
    float linv = 1.0f / (l_run * a1 + l2 * a2);
#pragma unroll
    for (int r = 0; r < 16; ++r) {
      int qi = (r & 3) + 8 * (r >> 2) + 4 * hi;
      float A1 = __shfl(a1, qi), A2 = __shfl(a2, qi), LI = __shfl(linv, qi);
      float e0 = (o0[r] * A1 + Ol[(wq * 32 + r) * 64 + lane] * A2) * LI;
      float e1 = (o1[r] * A1 + Ol[(wq * 32 + 16 + r) * 64 + lane] * A2) * LI;
      size_t base = ((size_t)bb * SEQ + q0 + qi) * EMBED + h * 64;
      AO[base + lq] = f2bf(e0);
      AO[base + 32 + lq] = f2bf(e1);
    }
  }
}

// ---------------- output projection GEMM ----------------
__global__ __launch_bounds__(256) void k_outproj(
    const unsigned short* __restrict__ AO, const unsigned short* __restrict__ Wo,
    const float* __restrict__ bias, float* __restrict__ out) {
  __shared__ __align__(16) unsigned short As[128 * 64];
  __shared__ __align__(16) unsigned short Bs[128 * 64];
  const int tid = threadIdx.x;
  const int lane = tid & 63, w = tid >> 6;
  const int wr = w >> 1, wc = w & 1;
  const int m0 = blockIdx.x * 128, n0 = blockIdx.y * 128;

  f32x4 acc[4][4];
#pragma unroll
  for (int a = 0; a < 4; ++a)
#pragma unroll
    for (int b = 0; b < 4; ++b) acc[a][b] = (f32x4){0.f, 0.f, 0.f, 0.f};

  for (int kt = 0; kt < 8; ++kt) {
#pragma unroll
    for (int i = 0; i < 4; ++i) {
      int cb = w * 256 + i * 64;
      int chunk = cb + lane;
      int row = chunk >> 3, cs = chunk & 7;
      gload_lds16(AO + (size_t)(m0 + row) * EMBED + kt * 64 + ((cs ^ (row & 7)) << 3),
                  (char*)As + cb * 16);
      gload_lds16(Wo + (size_t)(n0 + row) * EMBED + kt * 64 + ((cs ^ (row & 7)) << 3),
                  (char*)Bs + cb * 16);
    }
    __syncthreads();
#pragma unroll
    for (int kk = 0; kk < 2; ++kk) {
      short8 af[4], bfr[4];
      int dc = kk * 4 + (lane >> 4);
#pragma unroll
      for (int mf = 0; mf < 4; ++mf) {
        int row = wr * 64 + mf * 16 + (lane & 15);
        af[mf] = *(const short8*)((const char*)As + row * 128 + ((dc ^ (row & 7)) << 4));
      }
#pragma unroll
      for (int nf = 0; nf < 4; ++nf) {
        int row = wc * 64 + nf * 16 + (lane & 15);
        bfr[nf] = *(const short8*)((const char*)Bs + row * 128 + ((dc ^ (row & 7)) << 4));
      }
#pragma unroll
      for (int mf = 0; mf < 4; ++mf)
#pragma unroll
        for (int nf = 0; nf < 4; ++nf)
          acc[mf][nf] = __builtin_amdgcn_mfma_f32_16x16x32_bf16(af[mf], bfr[nf], acc[mf][nf], 0, 0, 0);
    }
    __syncthreads();
  }

#pragma unroll
  for (int mf = 0; mf < 4; ++mf)
#pragma unroll
    for (int nf = 0; nf < 4; ++nf) {
      int ncol = n0 + wc * 64 + nf * 16 + (lane & 15);
      float bv = bias[ncol];
#pragma unroll
      for (int r = 0; r < 4; ++r) {
        int mrow = m0 + wr * 64 + mf * 16 + (lane >> 4) * 4 + r;
        out[(size_t)mrow * EMBED + ncol] = acc[mf][nf][r] + bv;
      }
    }
}

extern "C" void kernel_launch(void* const* d_in, const int* in_sizes, int n_in,
                              void* d_out, int out_size, void* d_ws, size_t ws_size,
                              hipStream_t stream) {
  const float* query = (const float*)d_in[0];
  const float* key   = (const float*)d_in[1];
  const float* value = (const float*)d_in[2];
  const float* win   = (const float*)d_in[3];
  const float* bin   = (const float*)d_in[4];
  const float* wout  = (const float*)d_in[5];
  const float* bout  = (const float*)d_in[6];
  float* out = (float*)d_out;

  char* ws = (char*)d_ws;
  unsigned short* Wbf  = (unsigned short*)(ws);              // 1.5 MB
  unsigned short* Wobf = (unsigned short*)(ws + 0x180000);   // 0.5 MB
  unsigned short* Qg   = (unsigned short*)(ws + 0x200000);   // 8 MB
  unsigned short* Kg   = (unsigned short*)(ws + 0xA00000);   // 8 MB
  unsigned short* VTg  = (unsigned short*)(ws + 0x1200000);  // 8 MB
  unsigned short* AO   = (unsigned short*)(ws + 0x1A00000);  // 8 MB

  k_cvtw<<<1024, 256, 0, stream>>>(win, Wbf, wout, Wobf);
  k_proj<<<dim3(64, 4, 3), 256, 0, stream>>>(query, key, value, Wbf, bin, Qg, Kg, VTg);
  k_attn<<<dim3(32, 32), 256, 0, stream>>>(Qg, Kg, VTg, AO);
  k_outproj<<<dim3(64, 4), 256, 0, stream>>>(AO, Wobf, bout, out);
}